// Round 15
// baseline (91.887 us; speedup 1.0000x reference)
//
#include <hip/hip_runtime.h>
#include <hip/hip_bf16.h>

typedef __attribute__((ext_vector_type(4))) float float4v;  // 4 fp32 acc
typedef __attribute__((ext_vector_type(2))) float floatx2;
typedef __attribute__((ext_vector_type(8))) int v8i;        // 32 B MX fragment

// z is pre-scaled by sqrt(2*log2(e)), so MFMA dot = 2*log2(e)*cos and
// exp(2*cos) = exp2(dot) directly — no multiply in the epilogue.
#define ZSCALE 1.6986436f
#define SCALE_ONE 127u   /* E8M0 biased exponent for 1.0 */

#if __has_builtin(__builtin_amdgcn_exp2f)
#define VEXP2(x) __builtin_amdgcn_exp2f(x)   /* raw v_exp_f32; args in [-2.95,2.95] */
#else
#define VEXP2(x) exp2f(x)
#endif

// HW fp8 (OCP e4m3) pack/unpack — bit-identical to what the MFMA decodes.
__device__ __forceinline__ unsigned short pack_fp8pair(float x, float y){
    int p = __builtin_amdgcn_cvt_pk_fp8_f32(x, y, 0, 0);
    return (unsigned short)(p & 0xFFFF);
}
__device__ __forceinline__ floatx2 unpack_fp8pair(unsigned short u){
    return __builtin_amdgcn_cvt_pk_f32_fp8((int)u, 0);
}

// K1 (prep): one wave per group, 4 groups per block.  (unchanged from R13/R14)
__global__ void k_prep(const float* __restrict__ f, const int* __restrict__ nc,
                       unsigned char* __restrict__ z8, float* __restrict__ t,
                       float* __restrict__ possum, float* __restrict__ selfs,
                       float* __restrict__ out, int* __restrict__ cnt,
                       int G, int nbx){
    int lane = threadIdx.x & 63;
    int g = blockIdx.x * 4 + (threadIdx.x >> 6);
    if (g >= G) return;
    if (g == 0){
        if (lane == 0) out[0] = 0.0f;
        for (int i = lane; i < nbx; i += 64) cnt[i] = 0;
    }
    int st = 0;
    {
        int i = lane;
        for (; i + 192 < g; i += 256)
            st += nc[i] + nc[i + 64] + nc[i + 128] + nc[i + 192];
        for (; i < g; i += 64) st += nc[i];
    }
    #pragma unroll
    for (int m = 1; m < 64; m <<= 1) st += __shfl_xor(st, m);
    int c = nc[g];
    for (int i = lane; i < c; i += 64) t[st + i] = 0.0f;

    if (c == 4){
        float2 v[4]; float ss[4];
        #pragma unroll
        for (int a = 0; a < 4; a++){
            v[a] = ((const float2*)(f + (size_t)(st + a) * 128))[lane];
            ss[a] = v[a].x * v[a].x + v[a].y * v[a].y;
        }
        #pragma unroll
        for (int m = 1; m < 64; m <<= 1){
            ss[0] += __shfl_xor(ss[0], m);
            ss[1] += __shfl_xor(ss[1], m);
            ss[2] += __shfl_xor(ss[2], m);
            ss[3] += __shfl_xor(ss[3], m);
        }
        float zx[4], zy[4];
        #pragma unroll
        for (int a = 0; a < 4; a++){
            float scale = ZSCALE / fmaxf(sqrtf(ss[a]), 1e-8f);
            unsigned short pk = pack_fp8pair(v[a].x * scale, v[a].y * scale);
            ((unsigned short*)(z8 + (size_t)(st + a) * 128))[lane] = pk;
            floatx2 d = unpack_fp8pair(pk);       // the SAME values k_gram sees
            zx[a] = d[0]; zy[a] = d[1];
        }
        float s[10];
        s[0] = zx[0]*zx[0] + zy[0]*zy[0];
        s[1] = zx[0]*zx[1] + zy[0]*zy[1];
        s[2] = zx[0]*zx[2] + zy[0]*zy[2];
        s[3] = zx[0]*zx[3] + zy[0]*zy[3];
        s[4] = zx[1]*zx[1] + zy[1]*zy[1];
        s[5] = zx[1]*zx[2] + zy[1]*zy[2];
        s[6] = zx[1]*zx[3] + zy[1]*zy[3];
        s[7] = zx[2]*zx[2] + zy[2]*zy[2];
        s[8] = zx[2]*zx[3] + zy[2]*zy[3];
        s[9] = zx[3]*zx[3] + zy[3]*zy[3];
        #pragma unroll
        for (int m = 1; m < 64; m <<= 1)
            #pragma unroll
            for (int u = 0; u < 10; u++) s[u] += __shfl_xor(s[u], m);
        if (lane == 0){
            float E0 = exp2f(s[0]), E1 = exp2f(s[1]), E2 = exp2f(s[2]), E3 = exp2f(s[3]);
            float E4 = exp2f(s[4]), E5 = exp2f(s[5]), E6 = exp2f(s[6]), E7 = exp2f(s[7]);
            float E8 = exp2f(s[8]), E9 = exp2f(s[9]);
            possum[st + 0] = E1 + E2 + E3;  selfs[st + 0] = E0;
            possum[st + 1] = E1 + E5 + E6;  selfs[st + 1] = E4;
            possum[st + 2] = E2 + E5 + E8;  selfs[st + 2] = E7;
            possum[st + 3] = E3 + E6 + E8;  selfs[st + 3] = E9;
        }
    } else {
        for (int r = 0; r < c; r++){
            const float2* fr = (const float2*)(f + (size_t)(st + r) * 128);
            float2 vv = fr[lane];
            float ss2 = vv.x * vv.x + vv.y * vv.y;
            #pragma unroll
            for (int m = 1; m < 64; m <<= 1) ss2 += __shfl_xor(ss2, m);
            float scale = ZSCALE / fmaxf(sqrtf(ss2), 1e-8f);
            ((unsigned short*)(z8 + (size_t)(st + r) * 128))[lane] =
                pack_fp8pair(vv.x * scale, vv.y * scale);
        }
        for (int a = 0; a < c; a++){
            floatx2 da = unpack_fp8pair(((unsigned short*)(z8 + (size_t)(st + a) * 128))[lane]);
            float pacc = 0.0f;
            for (int b = 0; b < c; b++){
                floatx2 db = unpack_fp8pair(((unsigned short*)(z8 + (size_t)(st + b) * 128))[lane]);
                float sdot = da[0] * db[0] + da[1] * db[1];
                #pragma unroll
                for (int m = 1; m < 64; m <<= 1) sdot += __shfl_xor(sdot, m);
                float e = exp2f(sdot);
                if (b == a){ if (lane == 0) selfs[st + a] = e; }
                else pacc += e;
            }
            if (lane == 0) possum[st + a] = pacc;
        }
    }
}

// K2: Gram row-sums — R14 MX structure with DOUBLED grid TLP (the one axis not
// yet tested in the cheap-per-block MX regime): grid (32 slabs, 32 col-chunks)
// = 1024 blocks = 4 blocks/CU = 4 waves/SIMD (vs 2), hiding the per-strip
// load->MFMA->exp chain across waves. Wave = 64 rows x 256 cols as 16 strips.
// One MX-scaled MFMA per 16x16 tile (v_mfma_scale_f32_16x16x128_f8f6f4,
// scale=1.0 -> bit-identical to non-scaled fp8; self-Gram k-permutation
// cancels between A and B). VEXP2 epilogue; fused finalize via returning
// atomics (no threadfence — R9: L2 writeback costs 2x). Device-scope atomics
// only. C/D layout (verified): col = lane&15, row_local = mi*16 + quad*4 + r.
// MX fragment: lane holds z8[base + (lane&15)][bytes (lane>>4)*32 .. +31].
__global__ __launch_bounds__(256) void k_gram(const unsigned char* __restrict__ z8,
                                              float* __restrict__ t,
                                              const float* __restrict__ possum,
                                              const float* __restrict__ selfs,
                                              int* __restrict__ cnt,
                                              float* __restrict__ out, int N){
    int tid  = threadIdx.x;
    int lane = tid & 63, w = tid >> 6;
    int quad = lane >> 4, l15 = lane & 15;
    int bx = blockIdx.x, nby = gridDim.y;
    int r0 = bx * 256 + w * 64;
    int c0 = blockIdx.y * 256;
    size_t lq = (size_t)l15 * 128 + quad * 32;   // 32-B per-lane MX fragment offset

    const unsigned char* za = z8 + (size_t)r0 * 128;
    v8i af[4];
    #pragma unroll
    for (int mi = 0; mi < 4; mi++)
        af[mi] = *(const v8i*)(za + (size_t)(mi * 16) * 128 + lq);

    float ts[4][4];
    #pragma unroll
    for (int mi = 0; mi < 4; mi++)
        #pragma unroll
        for (int r = 0; r < 4; r++) ts[mi][r] = 0.0f;

    const unsigned char* zp = z8 + (size_t)c0 * 128 + lq;
    #pragma unroll 1
    for (int s = 0; s < 16; s++){
        v8i bf = *(const v8i*)(zp);
        float4v acc[4];
        #pragma unroll
        for (int mi = 0; mi < 4; mi++) acc[mi] = (float4v){0.0f, 0.0f, 0.0f, 0.0f};
        #pragma unroll
        for (int mi = 0; mi < 4; mi++)
            acc[mi] = __builtin_amdgcn_mfma_scale_f32_16x16x128_f8f6f4(
                af[mi], bf, acc[mi], 0, 0, 0, SCALE_ONE, 0, SCALE_ONE);
        #pragma unroll
        for (int mi = 0; mi < 4; mi++)
            #pragma unroll
            for (int r = 0; r < 4; r++)
                ts[mi][r] += VEXP2(acc[mi][r]);
        zp += 16 * 128;   // next 16-col strip (fp8 row = 128 B)
    }

    // reduce across the 16 column-lanes (same quad); returning atomics, ack consumed
    float ack = 0.0f;
    #pragma unroll
    for (int mi = 0; mi < 4; mi++)
        #pragma unroll
        for (int r = 0; r < 4; r++){
            float v = ts[mi][r];
            v += __shfl_xor(v, 1);
            v += __shfl_xor(v, 2);
            v += __shfl_xor(v, 4);
            v += __shfl_xor(v, 8);
            if (l15 == 0) ack += atomicAdd(&t[r0 + mi * 16 + quad * 4 + r], v);
        }
    if (ack == -1.0f) out[0] = 0.0f;   // never taken; keeps the returning form

    __syncthreads();   // all 4 waves' t-atomics acknowledged

    __shared__ int lastflag;
    if (tid == 0) lastflag = (atomicAdd(&cnt[bx], 1) == nby - 1);
    __syncthreads();
    if (lastflag){
        int r = bx * 256 + tid;     // 256 rows per slab, one per thread
        float s = 0.0f;
        if (r < N){
            float tv = atomicAdd(&t[r], 0.0f);   // coherent read of completed row sum
            float p  = possum[r];
            float nn = tv - p - selfs[r];
            s = logf(nn) - logf(p);
        }
        #pragma unroll
        for (int m = 1; m < 64; m <<= 1) s += __shfl_xor(s, m);
        __shared__ float red[4];
        if ((tid & 63) == 0) red[tid >> 6] = s;
        __syncthreads();
        if (tid == 0) atomicAdd(out, (red[0] + red[1] + red[2] + red[3]) / (float)N);
    }
}

extern "C" void kernel_launch(void* const* d_in, const int* in_sizes, int n_in,
                              void* d_out, int out_size, void* d_ws, size_t ws_size,
                              hipStream_t stream){
    const float* f  = (const float*)d_in[0];
    const int*   nc = (const int*)d_in[1];
    int N = in_sizes[0] / 128;   // 8192
    int G = in_sizes[1];         // 2048
    int nbx = N / 256;           // 32 row-slabs

    unsigned char* z8 = (unsigned char*)d_ws;                     // N*128 B fp8 z (pre-scaled)
    float* t     = (float*)((char*)d_ws + (size_t)N * 128);       // N fp32
    float* pos   = t + N;
    float* selfs = pos + N;
    int*   cnt   = (int*)(selfs + N);                             // nbx ints
    float* out   = (float*)d_out;

    k_prep<<<(G + 3) / 4, 256, 0, stream>>>(f, nc, z8, t, pos, selfs, out, cnt, G, nbx);
    dim3 grid(nbx, N / 256);
    k_gram<<<grid, 256, 0, stream>>>(z8, t, pos, selfs, cnt, out, N);
}

// Round 16
// 88.456 us; speedup vs baseline: 1.0388x; 1.0388x over previous
//
#include <hip/hip_runtime.h>
#include <hip/hip_bf16.h>

typedef __attribute__((ext_vector_type(4))) float float4v;  // 4 fp32 acc
typedef __attribute__((ext_vector_type(2))) float floatx2;
typedef __attribute__((ext_vector_type(8))) int v8i;        // 32 B MX fragment

// z is pre-scaled by sqrt(2*log2(e)), so MFMA dot = 2*log2(e)*cos and
// exp(2*cos) = exp2(dot) directly — no multiply in the epilogue.
#define ZSCALE 1.6986436f
#define SCALE_ONE 127u   /* E8M0 biased exponent for 1.0 */

#if __has_builtin(__builtin_amdgcn_exp2f)
#define VEXP2(x) __builtin_amdgcn_exp2f(x)   /* raw v_exp_f32; args in [-2.95,2.95] */
#else
#define VEXP2(x) exp2f(x)
#endif

// HW fp8 (OCP e4m3) pack/unpack — bit-identical to what the MFMA decodes.
__device__ __forceinline__ unsigned short pack_fp8pair(float x, float y){
    int p = __builtin_amdgcn_cvt_pk_fp8_f32(x, y, 0, 0);
    return (unsigned short)(p & 0xFFFF);
}
__device__ __forceinline__ floatx2 unpack_fp8pair(unsigned short u){
    return __builtin_amdgcn_cvt_pk_f32_fp8((int)u, 0);
}

// K1 (prep): one wave per group, 4 groups per block.
// Normalize rows (fp32 norm clamp 1e-8), scale ZSCALE, quantize fp8 e4m3 (HW cvt),
// store packed (row = 128 B); zero t rows; pos/self from fp32 dots of the SAME
// fp8-dequantized z (consistent with MFMA sums). Fast path c==4.
// Group-0 wave also zeroes out[0] and the per-slab counters.
__global__ void k_prep(const float* __restrict__ f, const int* __restrict__ nc,
                       unsigned char* __restrict__ z8, float* __restrict__ t,
                       float* __restrict__ possum, float* __restrict__ selfs,
                       float* __restrict__ out, int* __restrict__ cnt,
                       int G, int nbx){
    int lane = threadIdx.x & 63;
    int g = blockIdx.x * 4 + (threadIdx.x >> 6);
    if (g >= G) return;
    if (g == 0){
        if (lane == 0) out[0] = 0.0f;
        for (int i = lane; i < nbx; i += 64) cnt[i] = 0;
    }
    int st = 0;
    {
        int i = lane;
        for (; i + 192 < g; i += 256)
            st += nc[i] + nc[i + 64] + nc[i + 128] + nc[i + 192];
        for (; i < g; i += 64) st += nc[i];
    }
    #pragma unroll
    for (int m = 1; m < 64; m <<= 1) st += __shfl_xor(st, m);
    int c = nc[g];
    for (int i = lane; i < c; i += 64) t[st + i] = 0.0f;

    if (c == 4){
        float2 v[4]; float ss[4];
        #pragma unroll
        for (int a = 0; a < 4; a++){
            v[a] = ((const float2*)(f + (size_t)(st + a) * 128))[lane];
            ss[a] = v[a].x * v[a].x + v[a].y * v[a].y;
        }
        #pragma unroll
        for (int m = 1; m < 64; m <<= 1){
            ss[0] += __shfl_xor(ss[0], m);
            ss[1] += __shfl_xor(ss[1], m);
            ss[2] += __shfl_xor(ss[2], m);
            ss[3] += __shfl_xor(ss[3], m);
        }
        float zx[4], zy[4];
        #pragma unroll
        for (int a = 0; a < 4; a++){
            float scale = ZSCALE / fmaxf(sqrtf(ss[a]), 1e-8f);
            unsigned short pk = pack_fp8pair(v[a].x * scale, v[a].y * scale);
            ((unsigned short*)(z8 + (size_t)(st + a) * 128))[lane] = pk;
            floatx2 d = unpack_fp8pair(pk);       // the SAME values k_gram sees
            zx[a] = d[0]; zy[a] = d[1];
        }
        float s[10];
        s[0] = zx[0]*zx[0] + zy[0]*zy[0];
        s[1] = zx[0]*zx[1] + zy[0]*zy[1];
        s[2] = zx[0]*zx[2] + zy[0]*zy[2];
        s[3] = zx[0]*zx[3] + zy[0]*zy[3];
        s[4] = zx[1]*zx[1] + zy[1]*zy[1];
        s[5] = zx[1]*zx[2] + zy[1]*zy[2];
        s[6] = zx[1]*zx[3] + zy[1]*zy[3];
        s[7] = zx[2]*zx[2] + zy[2]*zy[2];
        s[8] = zx[2]*zx[3] + zy[2]*zy[3];
        s[9] = zx[3]*zx[3] + zy[3]*zy[3];
        #pragma unroll
        for (int m = 1; m < 64; m <<= 1)
            #pragma unroll
            for (int u = 0; u < 10; u++) s[u] += __shfl_xor(s[u], m);
        if (lane == 0){
            float E0 = exp2f(s[0]), E1 = exp2f(s[1]), E2 = exp2f(s[2]), E3 = exp2f(s[3]);
            float E4 = exp2f(s[4]), E5 = exp2f(s[5]), E6 = exp2f(s[6]), E7 = exp2f(s[7]);
            float E8 = exp2f(s[8]), E9 = exp2f(s[9]);
            possum[st + 0] = E1 + E2 + E3;  selfs[st + 0] = E0;
            possum[st + 1] = E1 + E5 + E6;  selfs[st + 1] = E4;
            possum[st + 2] = E2 + E5 + E8;  selfs[st + 2] = E7;
            possum[st + 3] = E3 + E6 + E8;  selfs[st + 3] = E9;
        }
    } else {
        for (int r = 0; r < c; r++){
            const float2* fr = (const float2*)(f + (size_t)(st + r) * 128);
            float2 vv = fr[lane];
            float ss2 = vv.x * vv.x + vv.y * vv.y;
            #pragma unroll
            for (int m = 1; m < 64; m <<= 1) ss2 += __shfl_xor(ss2, m);
            float scale = ZSCALE / fmaxf(sqrtf(ss2), 1e-8f);
            ((unsigned short*)(z8 + (size_t)(st + r) * 128))[lane] =
                pack_fp8pair(vv.x * scale, vv.y * scale);
        }
        for (int a = 0; a < c; a++){
            floatx2 da = unpack_fp8pair(((unsigned short*)(z8 + (size_t)(st + a) * 128))[lane]);
            float pacc = 0.0f;
            for (int b = 0; b < c; b++){
                floatx2 db = unpack_fp8pair(((unsigned short*)(z8 + (size_t)(st + b) * 128))[lane]);
                float sdot = da[0] * db[0] + da[1] * db[1];
                #pragma unroll
                for (int m = 1; m < 64; m <<= 1) sdot += __shfl_xor(sdot, m);
                float e = exp2f(sdot);
                if (b == a){ if (lane == 0) selfs[st + a] = e; }
                else pacc += e;
            }
            if (lane == 0) possum[st + a] = pacc;
        }
    }
}

// K2: Gram row-sums — BEST MEASURED CONFIG (R14, 89.0 µs total):
//  * 512-block geometry: grid (32 slabs, 16 col-chunks); wave = 64 rows x 512
//    cols as 32 strips of 16. (R15 measured: 1024 blocks / 256-col chunks is
//    ~3 µs WORSE — extra A-gathers + doubled B-traffic/atomics beat the added
//    latency hiding. 512 is the confirmed optimum on both sides.)
//  * ONE MX-scaled MFMA per 16x16 tile (v_mfma_scale_f32_16x16x128_f8f6f4,
//    scale=1.0 -> bit-identical to non-scaled fp8; self-Gram k-permutation
//    cancels between identically-loaded A and B fragments).
//  * VEXP2 epilogue: 1 v_exp + 1 v_add per element.
//  * fused finalize via returning atomics (no threadfence — R9: L2 writeback
//    costs 2x wall). Device-scope atomics only; no dispatch-order assumptions.
// C/D layout (verified): col = lane&15, row_local = mi*16 + quad*4 + r.
// MX fragment: lane holds z8[base + (lane&15)][bytes (lane>>4)*32 .. +31].
__global__ __launch_bounds__(256) void k_gram(const unsigned char* __restrict__ z8,
                                              float* __restrict__ t,
                                              const float* __restrict__ possum,
                                              const float* __restrict__ selfs,
                                              int* __restrict__ cnt,
                                              float* __restrict__ out, int N){
    int tid  = threadIdx.x;
    int lane = tid & 63, w = tid >> 6;
    int quad = lane >> 4, l15 = lane & 15;
    int bx = blockIdx.x, nby = gridDim.y;
    int r0 = bx * 256 + w * 64;
    int c0 = blockIdx.y * 512;
    size_t lq = (size_t)l15 * 128 + quad * 32;   // 32-B per-lane MX fragment offset

    const unsigned char* za = z8 + (size_t)r0 * 128;
    v8i af[4];
    #pragma unroll
    for (int mi = 0; mi < 4; mi++)
        af[mi] = *(const v8i*)(za + (size_t)(mi * 16) * 128 + lq);

    float ts[4][4];
    #pragma unroll
    for (int mi = 0; mi < 4; mi++)
        #pragma unroll
        for (int r = 0; r < 4; r++) ts[mi][r] = 0.0f;

    const unsigned char* zp = z8 + (size_t)c0 * 128 + lq;
    #pragma unroll 1
    for (int s = 0; s < 32; s++){
        v8i bf = *(const v8i*)(zp);
        float4v acc[4];
        #pragma unroll
        for (int mi = 0; mi < 4; mi++) acc[mi] = (float4v){0.0f, 0.0f, 0.0f, 0.0f};
        #pragma unroll
        for (int mi = 0; mi < 4; mi++)
            acc[mi] = __builtin_amdgcn_mfma_scale_f32_16x16x128_f8f6f4(
                af[mi], bf, acc[mi], 0, 0, 0, SCALE_ONE, 0, SCALE_ONE);
        #pragma unroll
        for (int mi = 0; mi < 4; mi++)
            #pragma unroll
            for (int r = 0; r < 4; r++)
                ts[mi][r] += VEXP2(acc[mi][r]);
        zp += 16 * 128;   // next 16-col strip (fp8 row = 128 B)
    }

    // reduce across the 16 column-lanes (same quad); returning atomics, ack consumed
    float ack = 0.0f;
    #pragma unroll
    for (int mi = 0; mi < 4; mi++)
        #pragma unroll
        for (int r = 0; r < 4; r++){
            float v = ts[mi][r];
            v += __shfl_xor(v, 1);
            v += __shfl_xor(v, 2);
            v += __shfl_xor(v, 4);
            v += __shfl_xor(v, 8);
            if (l15 == 0) ack += atomicAdd(&t[r0 + mi * 16 + quad * 4 + r], v);
        }
    if (ack == -1.0f) out[0] = 0.0f;   // never taken; keeps the returning form

    __syncthreads();   // all 4 waves' t-atomics acknowledged

    __shared__ int lastflag;
    if (tid == 0) lastflag = (atomicAdd(&cnt[bx], 1) == nby - 1);
    __syncthreads();
    if (lastflag){
        int r = bx * 256 + tid;     // 256 rows per slab, one per thread
        float s = 0.0f;
        if (r < N){
            float tv = atomicAdd(&t[r], 0.0f);   // coherent read of completed row sum
            float p  = possum[r];
            float nn = tv - p - selfs[r];
            s = logf(nn) - logf(p);
        }
        #pragma unroll
        for (int m = 1; m < 64; m <<= 1) s += __shfl_xor(s, m);
        __shared__ float red[4];
        if ((tid & 63) == 0) red[tid >> 6] = s;
        __syncthreads();
        if (tid == 0) atomicAdd(out, (red[0] + red[1] + red[2] + red[3]) / (float)N);
    }
}

extern "C" void kernel_launch(void* const* d_in, const int* in_sizes, int n_in,
                              void* d_out, int out_size, void* d_ws, size_t ws_size,
                              hipStream_t stream){
    const float* f  = (const float*)d_in[0];
    const int*   nc = (const int*)d_in[1];
    int N = in_sizes[0] / 128;   // 8192
    int G = in_sizes[1];         // 2048
    int nbx = N / 256;           // 32 row-slabs

    unsigned char* z8 = (unsigned char*)d_ws;                     // N*128 B fp8 z (pre-scaled)
    float* t     = (float*)((char*)d_ws + (size_t)N * 128);       // N fp32
    float* pos   = t + N;
    float* selfs = pos + N;
    int*   cnt   = (int*)(selfs + N);                             // nbx ints
    float* out   = (float*)d_out;

    k_prep<<<(G + 3) / 4, 256, 0, stream>>>(f, nc, z8, t, pos, selfs, out, cnt, G, nbx);
    dim3 grid(nbx, N / 512);
    k_gram<<<grid, 256, 0, stream>>>(z8, t, pos, selfs, cnt, out, N);
}